// Round 21
// baseline (184.398 us; speedup 1.0000x reference)
//
#include <hip/hip_runtime.h>
#include <hip/hip_bf16.h>

#define HS 64
#define NH 16
#define NG 16
#define TT 2048
#define CC 1024
#define BBATCH 4
#define TG 128
#define SS 129   // TG+1

typedef __attribute__((ext_vector_type(8))) short bf16x8;
typedef __attribute__((ext_vector_type(4))) float f32x4;

__device__ __forceinline__ float bf2f(ushort u) {
  return __uint_as_float(((unsigned)u) << 16);
}
__device__ __forceinline__ ushort f2bf(float f) {
  unsigned x = __float_as_uint(f);
  x += 0x7fff + ((x >> 16) & 1);
  return (ushort)(x >> 16);
}
__device__ __forceinline__ unsigned pk2(float a, float b) {
  return (unsigned)f2bf(a) | ((unsigned)f2bf(b) << 16);
}
__device__ __forceinline__ bf16x8 mk8(ushort4 a0, ushort4 a1) {
  bf16x8 v;
  v[0] = (short)a0.x; v[1] = (short)a0.y; v[2] = (short)a0.z; v[3] = (short)a0.w;
  v[4] = (short)a1.x; v[5] = (short)a1.y; v[6] = (short)a1.z; v[7] = (short)a1.w;
  return v;
}

// ---------------- fp32 -> bf16 convert (weights only; x handled in-GEMM) ----------------
__global__ void cvt_w(const float* __restrict__ wa, const float* __restrict__ wp,
                      ushort* __restrict__ wab, ushort* __restrict__ wpb) {
  const int stride = gridDim.x * blockDim.x;
  for (int i = blockIdx.x * blockDim.x + threadIdx.x; i < 1048576; i += stride) {
    const float* src; ushort* dst; int off;
    if (i < 786432) { src = wa; dst = wab; off = i; }
    else { src = wp; dst = wpb; off = i - 786432; }
    float4 v = ((const float4*)src)[off];
    ushort4 o;
    o.x = f2bf(v.x); o.y = f2bf(v.y); o.z = f2bf(v.z); o.w = f2bf(v.w);
    ((ushort4*)dst)[off] = o;
  }
}

// ---------------- qkv GEMM, 128x384 tile, A read as fp32 (fused convert) ----------------
// 512 threads, 8 waves (2M x 4N), 64x96 per wave, reg-staged pad-68 LDS, early-load.
__global__ __launch_bounds__(512) void gemm_qkv3f(const float* __restrict__ Af,
                                                  const ushort* __restrict__ Bw,
                                                  ushort* __restrict__ Cout) {
  const int Kd = 1024, Nd = 3072;
  __shared__ ushort As[128][68];
  __shared__ ushort Bs[384][68];
  const int m0 = blockIdx.y * 128;
  const int n0 = blockIdx.x * 384;
  const int tid = threadIdx.x;
  const int lane = tid & 63;
  const int wv = tid >> 6;
  const int wm = wv >> 2, wn = wv & 3;
  const int lo = lane & 15, hi = lane >> 4;
  const int rb = tid >> 3;            // 0..63
  const int c8 = (tid & 7) * 8;

  f32x4 acc[4][6];
#pragma unroll
  for (int i = 0; i < 4; ++i)
#pragma unroll
    for (int j = 0; j < 6; ++j) acc[i][j] = (f32x4)0.0f;

  float4 a0l, a0h, a1l, a1h;
  uint4 v2, v3, v4, v5, v6, v7;
#define LOADQ(k0_)                                                              \
  {                                                                             \
    a0l = *(const float4*)(Af + (size_t)(m0 + rb) * Kd + (k0_) + c8);           \
    a0h = *(const float4*)(Af + (size_t)(m0 + rb) * Kd + (k0_) + c8 + 4);       \
    a1l = *(const float4*)(Af + (size_t)(m0 + rb + 64) * Kd + (k0_) + c8);      \
    a1h = *(const float4*)(Af + (size_t)(m0 + rb + 64) * Kd + (k0_) + c8 + 4);  \
    v2 = *(const uint4*)(Bw + (size_t)(n0 + rb) * Kd + (k0_) + c8);             \
    v3 = *(const uint4*)(Bw + (size_t)(n0 + rb + 64) * Kd + (k0_) + c8);        \
    v4 = *(const uint4*)(Bw + (size_t)(n0 + rb + 128) * Kd + (k0_) + c8);       \
    v5 = *(const uint4*)(Bw + (size_t)(n0 + rb + 192) * Kd + (k0_) + c8);       \
    v6 = *(const uint4*)(Bw + (size_t)(n0 + rb + 256) * Kd + (k0_) + c8);       \
    v7 = *(const uint4*)(Bw + (size_t)(n0 + rb + 320) * Kd + (k0_) + c8);       \
  }
#define STOREQ                                                                  \
  {                                                                             \
    *(uint2*)&As[rb][c8]            = make_uint2(pk2(a0l.x, a0l.y), pk2(a0l.z, a0l.w)); \
    *(uint2*)&As[rb][c8 + 4]        = make_uint2(pk2(a0h.x, a0h.y), pk2(a0h.z, a0h.w)); \
    *(uint2*)&As[rb + 64][c8]       = make_uint2(pk2(a1l.x, a1l.y), pk2(a1l.z, a1l.w)); \
    *(uint2*)&As[rb + 64][c8 + 4]   = make_uint2(pk2(a1h.x, a1h.y), pk2(a1h.z, a1h.w)); \
    *(uint2*)&Bs[rb][c8]            = make_uint2(v2.x, v2.y);                   \
    *(uint2*)&Bs[rb][c8 + 4]        = make_uint2(v2.z, v2.w);                   \
    *(uint2*)&Bs[rb + 64][c8]       = make_uint2(v3.x, v3.y);                   \
    *(uint2*)&Bs[rb + 64][c8 + 4]   = make_uint2(v3.z, v3.w);                   \
    *(uint2*)&Bs[rb + 128][c8]      = make_uint2(v4.x, v4.y);                   \
    *(uint2*)&Bs[rb + 128][c8 + 4]  = make_uint2(v4.z, v4.w);                   \
    *(uint2*)&Bs[rb + 192][c8]      = make_uint2(v5.x, v5.y);                   \
    *(uint2*)&Bs[rb + 192][c8 + 4]  = make_uint2(v5.z, v5.w);                   \
    *(uint2*)&Bs[rb + 256][c8]      = make_uint2(v6.x, v6.y);                   \
    *(uint2*)&Bs[rb + 256][c8 + 4]  = make_uint2(v6.z, v6.w);                   \
    *(uint2*)&Bs[rb + 320][c8]      = make_uint2(v7.x, v7.y);                   \
    *(uint2*)&Bs[rb + 320][c8 + 4]  = make_uint2(v7.z, v7.w);                   \
  }

  LOADQ(0)
  for (int t = 0; t < 16; ++t) {
    __syncthreads();
    STOREQ
    __syncthreads();
    if (t < 15) LOADQ((t + 1) * 64)   // overlaps with the MFMA section below
#pragma unroll
    for (int kk = 0; kk < 64; kk += 32) {
      bf16x8 af[4], bfr[6];
#pragma unroll
      for (int i = 0; i < 4; ++i) {
        int r = wm * 64 + i * 16 + lo;
        af[i] = mk8(*(const ushort4*)&As[r][kk + 4 * hi],
                    *(const ushort4*)&As[r][kk + 16 + 4 * hi]);
      }
#pragma unroll
      for (int j = 0; j < 6; ++j) {
        int r = wn * 96 + j * 16 + lo;
        bfr[j] = mk8(*(const ushort4*)&Bs[r][kk + 4 * hi],
                     *(const ushort4*)&Bs[r][kk + 16 + 4 * hi]);
      }
#pragma unroll
      for (int i = 0; i < 4; ++i)
#pragma unroll
        for (int j = 0; j < 6; ++j)
          acc[i][j] = __builtin_amdgcn_mfma_f32_16x16x32_bf16(af[i], bfr[j], acc[i][j], 0, 0, 0);
    }
  }
#undef LOADQ
#undef STOREQ

#pragma unroll
  for (int i = 0; i < 4; ++i) {
    int row = m0 + wm * 64 + i * 16 + 4 * hi;
#pragma unroll
    for (int j = 0; j < 6; ++j) {
      int col = n0 + wn * 96 + j * 16 + lo;
#pragma unroll
      for (int r = 0; r < 4; ++r)
        Cout[(size_t)(row + r) * Nd + col] = f2bf(acc[i][j][r]);
    }
  }
}

// ---------------- proj GEMM, 128x256 tile (A-reuse + early-load), fp32 out ----------------
__global__ __launch_bounds__(512) void gemm_proj2(const ushort* __restrict__ A,
                                                  const ushort* __restrict__ Bw,
                                                  float* __restrict__ Cout) {
  const int Kd = 1024, Nd = 1024;
  __shared__ ushort As[128][68];
  __shared__ ushort Bs[256][68];
  const int m0 = blockIdx.y * 128;
  const int n0 = blockIdx.x * 256;
  const int tid = threadIdx.x;
  const int lane = tid & 63;
  const int wv = tid >> 6;
  const int wm = wv >> 2, wn = wv & 3;
  const int lo = lane & 15, hi = lane >> 4;
  const int rb = tid >> 3;            // 0..63
  const int c8 = (tid & 7) * 8;

  f32x4 acc[4][4];
#pragma unroll
  for (int i = 0; i < 4; ++i)
#pragma unroll
    for (int j = 0; j < 4; ++j) acc[i][j] = (f32x4)0.0f;

  uint4 v0, v1, v2, v3, v4, v5;
#define LOADP(k0_)                                                              \
  {                                                                             \
    v0 = *(const uint4*)(A + (size_t)(m0 + rb) * Kd + (k0_) + c8);              \
    v1 = *(const uint4*)(A + (size_t)(m0 + rb + 64) * Kd + (k0_) + c8);         \
    v2 = *(const uint4*)(Bw + (size_t)(n0 + rb) * Kd + (k0_) + c8);             \
    v3 = *(const uint4*)(Bw + (size_t)(n0 + rb + 64) * Kd + (k0_) + c8);        \
    v4 = *(const uint4*)(Bw + (size_t)(n0 + rb + 128) * Kd + (k0_) + c8);       \
    v5 = *(const uint4*)(Bw + (size_t)(n0 + rb + 192) * Kd + (k0_) + c8);       \
  }
#define STOREP                                                                  \
  {                                                                             \
    *(uint2*)&As[rb][c8]            = make_uint2(v0.x, v0.y);                   \
    *(uint2*)&As[rb][c8 + 4]        = make_uint2(v0.z, v0.w);                   \
    *(uint2*)&As[rb + 64][c8]       = make_uint2(v1.x, v1.y);                   \
    *(uint2*)&As[rb + 64][c8 + 4]   = make_uint2(v1.z, v1.w);                   \
    *(uint2*)&Bs[rb][c8]            = make_uint2(v2.x, v2.y);                   \
    *(uint2*)&Bs[rb][c8 + 4]        = make_uint2(v2.z, v2.w);                   \
    *(uint2*)&Bs[rb + 64][c8]       = make_uint2(v3.x, v3.y);                   \
    *(uint2*)&Bs[rb + 64][c8 + 4]   = make_uint2(v3.z, v3.w);                   \
    *(uint2*)&Bs[rb + 128][c8]      = make_uint2(v4.x, v4.y);                   \
    *(uint2*)&Bs[rb + 128][c8 + 4]  = make_uint2(v4.z, v4.w);                   \
    *(uint2*)&Bs[rb + 192][c8]      = make_uint2(v5.x, v5.y);                   \
    *(uint2*)&Bs[rb + 192][c8 + 4]  = make_uint2(v5.z, v5.w);                   \
  }

  LOADP(0)
  for (int t = 0; t < 16; ++t) {
    __syncthreads();
    STOREP
    __syncthreads();
    if (t < 15) LOADP((t + 1) * 64)
#pragma unroll
    for (int kk = 0; kk < 64; kk += 32) {
      bf16x8 af[4], bfr[4];
#pragma unroll
      for (int i = 0; i < 4; ++i) {
        int r = wm * 64 + i * 16 + lo;
        af[i] = mk8(*(const ushort4*)&As[r][kk + 4 * hi],
                    *(const ushort4*)&As[r][kk + 16 + 4 * hi]);
      }
#pragma unroll
      for (int j = 0; j < 4; ++j) {
        int r = wn * 64 + j * 16 + lo;
        bfr[j] = mk8(*(const ushort4*)&Bs[r][kk + 4 * hi],
                     *(const ushort4*)&Bs[r][kk + 16 + 4 * hi]);
      }
#pragma unroll
      for (int i = 0; i < 4; ++i)
#pragma unroll
        for (int j = 0; j < 4; ++j)
          acc[i][j] = __builtin_amdgcn_mfma_f32_16x16x32_bf16(af[i], bfr[j], acc[i][j], 0, 0, 0);
    }
  }
#undef LOADP
#undef STOREP

#pragma unroll
  for (int i = 0; i < 4; ++i) {
    int row = m0 + wm * 64 + i * 16 + 4 * hi;
#pragma unroll
    for (int j = 0; j < 4; ++j) {
      int col = n0 + wn * 64 + j * 16 + lo;
#pragma unroll
      for (int r = 0; r < 4; ++r)
        Cout[(size_t)(row + r) * Nd + col] = acc[i][j][r];
    }
  }
}

// ---------------- fused RoPE + mean + causal attention per (b,h,g) — 8 waves (r16) ----------------
__global__ __launch_bounds__(512, 4) void attn1f(const ushort* __restrict__ qkv,
                                                 const float* __restrict__ fc,
                                                 const float* __restrict__ fs,
                                                 ushort* __restrict__ xo, float* __restrict__ attm,
                                                 float* __restrict__ yq, float* __restrict__ yk) {
  __shared__ ushort qs[144][68];
  __shared__ ushort ks[144][68];
  __shared__ ushort vt[64][148];     // V^T: vt[d][key]
  __shared__ ushort obuf[8][16][68]; // phase C; aliased as redL (6 KB) for the mean reduce
  float (*redL)[8][24] = reinterpret_cast<float(*)[8][24]>(&obuf[0][0][0]);
  const int blk = blockIdx.x;
  const int g = blk & 15, h = (blk >> 4) & 15, b = blk >> 8;
  const int tid = threadIdx.x;
  const int lane = tid & 63, wv = tid >> 6;
  const int lo = lane & 15, hi = lane >> 4;

  if (tid < 320) {
    int d = tid / 5, ch = (tid % 5) * 4;
    *(ushort4*)&vt[d][128 + ch] = make_ushort4(0, 0, 0, 0);
  }

  const size_t rowbase = (size_t)(b * TT + g * TG) * (3 * CC) + h * HS;
  const int srow = tid >> 3;          // 0..63
  const int c8 = (tid & 7) * 8;
  float msq[8], msk[8], msv[8];
#pragma unroll
  for (int j = 0; j < 8; ++j) { msq[j] = 0.f; msk[j] = 0.f; msv[j] = 0.f; }
#pragma unroll
  for (int it = 0; it < 6; ++it) {
    const int part = it >> 1;          // 0:q 1:k 2:v
    const int s = srow + 64 * (it & 1);
    uint4 w = *(const uint4*)(qkv + rowbase + (size_t)s * (3 * CC) + part * CC + c8);
    ushort e[8];
    *(uint4*)e = w;
    if (part == 2) {
#pragma unroll
      for (int j = 0; j < 8; ++j) { msv[j] += bf2f(e[j]); vt[c8 + j][s] = e[j]; }
    } else {
      const int ts = g * TG + s;
      float4 cv = *(const float4*)&fc[ts * 32 + (c8 >> 1)];
      float4 sv = *(const float4*)&fs[ts * 32 + (c8 >> 1)];
      float a0 = bf2f(e[0]), a1 = bf2f(e[1]), a2 = bf2f(e[2]), a3 = bf2f(e[3]);
      float a4 = bf2f(e[4]), a5 = bf2f(e[5]), a6 = bf2f(e[6]), a7 = bf2f(e[7]);
      float r0 = a0 * cv.x - a1 * sv.x, r1 = a0 * sv.x + a1 * cv.x;
      float r2 = a2 * cv.y - a3 * sv.y, r3 = a2 * sv.y + a3 * cv.y;
      float r4 = a4 * cv.z - a5 * sv.z, r5 = a4 * sv.z + a5 * cv.z;
      float r6 = a6 * cv.w - a7 * sv.w, r7 = a6 * sv.w + a7 * cv.w;
      uint4 o;
      o.x = pk2(r0, r1);
      o.y = pk2(r2, r3);
      o.z = pk2(r4, r5);
      o.w = pk2(r6, r7);
      if (part == 0) {
        *(uint4*)&qs[s][c8] = o;
        msq[0] += r0; msq[1] += r1; msq[2] += r2; msq[3] += r3;
        msq[4] += r4; msq[5] += r5; msq[6] += r6; msq[7] += r7;
      } else {
        *(uint4*)&ks[s][c8] = o;
        msk[0] += r0; msk[1] += r1; msk[2] += r2; msk[3] += r3;
        msk[4] += r4; msk[5] += r5; msk[6] += r6; msk[7] += r7;
      }
    }
  }
#pragma unroll
  for (int j = 0; j < 8; ++j) {
    msq[j] += __shfl_xor(msq[j], 8); msq[j] += __shfl_xor(msq[j], 16); msq[j] += __shfl_xor(msq[j], 32);
    msk[j] += __shfl_xor(msk[j], 8); msk[j] += __shfl_xor(msk[j], 16); msk[j] += __shfl_xor(msk[j], 32);
    msv[j] += __shfl_xor(msv[j], 8); msv[j] += __shfl_xor(msv[j], 16); msv[j] += __shfl_xor(msv[j], 32);
  }
  if (lane < 8) {
#pragma unroll
    for (int j = 0; j < 8; ++j) {
      redL[wv][lane][j] = msq[j];
      redL[wv][lane][8 + j] = msk[j];
      redL[wv][lane][16 + j] = msv[j];
    }
  }
  __syncthreads();
  if (tid < 64) {
    const int cg = tid >> 3, j = tid & 7;
    float mq = 0.f, mk2 = 0.f, mv = 0.f;
#pragma unroll
    for (int w = 0; w < 8; ++w) {
      mq += redL[w][cg][j];
      mk2 += redL[w][cg][8 + j];
      mv += redL[w][cg][16 + j];
    }
    mq *= (1.0f / 128.0f); mk2 *= (1.0f / 128.0f); mv *= (1.0f / 128.0f);
    qs[128][tid] = f2bf(mq);
    ks[128][tid] = f2bf(mk2);
    vt[tid][128] = f2bf(mv);
    if (g < 15) {
      size_t yo = ((size_t)(b * 16 + h) * 15 + g) * 64 + tid;
      yq[yo] = mq; yk[yo] = mk2;
    }
  }
  __syncthreads();

#pragma unroll
  for (int ti = 0; ti < 2; ++ti) {
    const int t = (ti == 0) ? (8 - wv) : ((wv == 7) ? 0 : -1);
    if (t < 0) continue;
    const int q0 = t * 16;

    bf16x8 bq[2];
#pragma unroll
    for (int k2 = 0; k2 < 2; ++k2)
      bq[k2] = mk8(*(const ushort4*)&qs[q0 + lo][k2 * 32 + 4 * hi],
                   *(const ushort4*)&qs[q0 + lo][k2 * 32 + 16 + 4 * hi]);

    f32x4 sc[9];
#pragma unroll
    for (int n = 0; n < 9; ++n) sc[n] = (f32x4)0.0f;
#pragma unroll
    for (int n = 0; n < 9; ++n) {
      if (n > t) continue;
#pragma unroll
      for (int k2 = 0; k2 < 2; ++k2) {
        bf16x8 ak = mk8(*(const ushort4*)&ks[n * 16 + lo][k2 * 32 + 4 * hi],
                        *(const ushort4*)&ks[n * 16 + lo][k2 * 32 + 16 + 4 * hi]);
        sc[n] = __builtin_amdgcn_mfma_f32_16x16x32_bf16(ak, bq[k2], sc[n], 0, 0, 0);
      }
    }

    const int qi = q0 + lo;
    float mx = -INFINITY;
#pragma unroll
    for (int n = 0; n < 9; ++n) {
      if (n > t) continue;
#pragma unroll
      for (int r = 0; r < 4; ++r) {
        int kj = n * 16 + 4 * hi + r;
        float v = (kj <= qi) ? sc[n][r] * 0.125f : -INFINITY;
        sc[n][r] = v;
        mx = fmaxf(mx, v);
      }
    }
    mx = fmaxf(mx, __shfl_xor(mx, 16));
    mx = fmaxf(mx, __shfl_xor(mx, 32));
    float sum = 0.f;
#pragma unroll
    for (int n = 0; n < 9; ++n) {
      if (n > t) continue;
#pragma unroll
      for (int r = 0; r < 4; ++r) {
        float e = __expf(sc[n][r] - mx);
        sc[n][r] = e;
        sum += e;
      }
    }
    sum += __shfl_xor(sum, 16);
    sum += __shfl_xor(sum, 32);
    const float inv = 1.0f / sum;

    f32x4 oac[4];
#pragma unroll
    for (int m = 0; m < 4; ++m) oac[m] = (f32x4)0.0f;
#pragma unroll
    for (int s2 = 0; s2 < 5; ++s2) {
      if (s2 > (t >> 1)) continue;
      const int kt1ok = (2 * s2 + 1 <= t);
      bf16x8 pb;
#pragma unroll
      for (int e = 0; e < 4; ++e) pb[e] = (short)f2bf(sc[2 * s2][e] * inv);
      if (kt1ok) {
#pragma unroll
        for (int e = 0; e < 4; ++e) pb[e + 4] = (short)f2bf(sc[2 * s2 + 1][e] * inv);
      } else {
#pragma unroll
        for (int e = 0; e < 4; ++e) pb[e + 4] = 0;
      }
#pragma unroll
      for (int m = 0; m < 4; ++m) {
        ushort4 a0 = *(const ushort4*)&vt[m * 16 + lo][32 * s2 + 4 * hi];
        ushort4 a1 = kt1ok ? *(const ushort4*)&vt[m * 16 + lo][32 * s2 + 16 + 4 * hi]
                           : make_ushort4(0, 0, 0, 0);
        oac[m] = __builtin_amdgcn_mfma_f32_16x16x32_bf16(mk8(a0, a1), pb, oac[m], 0, 0, 0);
      }
    }

    if (t < 8) {
#pragma unroll
      for (int m = 0; m < 4; ++m)
#pragma unroll
        for (int r = 0; r < 4; ++r)
          obuf[wv][lo][m * 16 + 4 * hi + r] = f2bf(oac[m][r]);
#pragma unroll
      for (int it = 0; it < 4; ++it) {
        int idx = lane + 64 * it;
        int r = idx >> 4;
        int c4 = (idx & 15) * 4;
        uint2 val = *(const uint2*)&obuf[wv][r][c4];
        int tok = g * TG + t * 16 + r;
        *(uint2*)(xo + ((size_t)(b * TT + tok)) * CC + h * HS + c4) = val;
      }
    } else {
      if (lo == 0) {
#pragma unroll
        for (int m = 0; m < 4; ++m)
#pragma unroll
          for (int r = 0; r < 4; ++r)
            attm[(size_t)blk * 64 + m * 16 + 4 * hi + r] = oac[m][r];
      }
    }
  }
}

// ---------------- second (tiny) causal attention over 15 group-mean tokens ----------------
__global__ __launch_bounds__(64) void attn2(const float* __restrict__ yq,
                                            const float* __restrict__ yk,
                                            const float* __restrict__ attm,
                                            float* __restrict__ yv) {
  __shared__ float qs2[15][64], ks2[15][64], avs[15][64], srow[16];
  int bh = blockIdx.x, lane = threadIdx.x;
  for (int j = 0; j < 15; ++j) {
    qs2[j][lane] = yq[((size_t)bh * 15 + j) * 64 + lane];
    ks2[j][lane] = yk[((size_t)bh * 15 + j) * 64 + lane];
    avs[j][lane] = attm[((size_t)bh * 16 + j) * 64 + lane];
  }
  __syncthreads();
  for (int i = 0; i < 15; ++i) {
    float qv = qs2[i][lane];
    for (int j = 0; j <= i; ++j) {
      float t = qv * ks2[j][lane];
#pragma unroll
      for (int off = 32; off > 0; off >>= 1) t += __shfl_xor(t, off);
      if (lane == 0) srow[j] = t * 0.125f;
    }
    __syncthreads();
    float mx = -INFINITY;
    for (int j = 0; j <= i; ++j) mx = fmaxf(mx, srow[j]);
    float den = 0;
    for (int j = 0; j <= i; ++j) den += __expf(srow[j] - mx);
    float inv = 1.0f / den;
    float o = 0;
    for (int j = 0; j <= i; ++j) o += __expf(srow[j] - mx) * inv * avs[j][lane];
    yv[((size_t)bh * 15 + i) * 64 + lane] = o;
    __syncthreads();
  }
}

extern "C" void kernel_launch(void* const* d_in, const int* in_sizes, int n_in,
                              void* d_out, int out_size, void* d_ws, size_t ws_size,
                              hipStream_t stream) {
  const float* x      = (const float*)d_in[0];
  const float* w_attn = (const float*)d_in[1];
  const float* w_proj = (const float*)d_in[2];
  const float* fc     = (const float*)d_in[3];
  const float* fs     = (const float*)d_in[4];
  float* out = (float*)d_out;

  char* ws = (char*)d_ws;
  ushort* xo   = (ushort*)(ws);               // attn1f output (16.8 MB)
  ushort* wab  = (ushort*)(ws + 16777216);
  float*  attm = (float*) (ws + 23068672);    // 262,144 B
  ushort* wpb  = (ushort*)(ws + 23330816);
  ushort* qkv  = (ushort*)(ws + 25427968);    // (B*T) x 3C bf16 -> end 75,759,616

  float* yq = out + 8388608;
  float* yk = out + 8450048;
  float* yv = out + 8511488;

  cvt_w<<<1024, 256, 0, stream>>>(w_attn, w_proj, wab, wpb);
  gemm_qkv3f<<<dim3(8, 64), 512, 0, stream>>>(x, wab, qkv);
  attn1f<<<1024, 512, 0, stream>>>(qkv, fc, fs, xo, attm, yq, yk);
  attn2<<<64, 64, 0, stream>>>(yq, yk, attm, yv);
  gemm_proj2<<<dim3(4, 64), 512, 0, stream>>>(xo, wpb, out);
}

// Round 22
// 176.801 us; speedup vs baseline: 1.0430x; 1.0430x over previous
//
#include <hip/hip_runtime.h>
#include <hip/hip_bf16.h>

#define HS 64
#define NH 16
#define NG 16
#define TT 2048
#define CC 1024
#define BBATCH 4
#define TG 128
#define SS 129   // TG+1

typedef __attribute__((ext_vector_type(8))) short bf16x8;
typedef __attribute__((ext_vector_type(4))) float f32x4;

__device__ __forceinline__ float bf2f(ushort u) {
  return __uint_as_float(((unsigned)u) << 16);
}
__device__ __forceinline__ ushort f2bf(float f) {
  unsigned x = __float_as_uint(f);
  x += 0x7fff + ((x >> 16) & 1);
  return (ushort)(x >> 16);
}
__device__ __forceinline__ bf16x8 mk8(ushort4 a0, ushort4 a1) {
  bf16x8 v;
  v[0] = (short)a0.x; v[1] = (short)a0.y; v[2] = (short)a0.z; v[3] = (short)a0.w;
  v[4] = (short)a1.x; v[5] = (short)a1.y; v[6] = (short)a1.z; v[7] = (short)a1.w;
  return v;
}

// ---------------- fused fp32 -> bf16 convert (x, w_attn, w_proj in one launch) ----------------
__global__ void cvt3(const float* __restrict__ x, const float* __restrict__ wa,
                     const float* __restrict__ wp, ushort* __restrict__ xb,
                     ushort* __restrict__ wab, ushort* __restrict__ wpb) {
  const int stride = gridDim.x * blockDim.x;
  for (int i = blockIdx.x * blockDim.x + threadIdx.x; i < 3145728; i += stride) {
    const float* src; ushort* dst; int off;
    if (i < 2097152) { src = x; dst = xb; off = i; }
    else if (i < 2883584) { src = wa; dst = wab; off = i - 2097152; }
    else { src = wp; dst = wpb; off = i - 2883584; }
    float4 v = ((const float4*)src)[off];
    ushort4 o;
    o.x = f2bf(v.x); o.y = f2bf(v.y); o.z = f2bf(v.z); o.w = f2bf(v.w);
    ((ushort4*)dst)[off] = o;
  }
}

// ---------------- bf16 GEMM (r2-proven reg-staged, pad-68):  C = A * Bw^T ----------------
template <bool OUT_BF16>
__global__ __launch_bounds__(256) void gemm_bt(const ushort* __restrict__ A,
                                               const ushort* __restrict__ Bw,
                                               void* __restrict__ Cout,
                                               int M, int N, int K) {
  __shared__ ushort As[128][68];
  __shared__ ushort Bs[128][68];
  const int m0 = blockIdx.y * 128;
  const int n0 = blockIdx.x * 128;
  const int tid = threadIdx.x;
  const int lane = tid & 63;
  const int wv = tid >> 6;
  const int wr = wv >> 1, wc = wv & 1;
  const int lo = lane & 15, hi = lane >> 4;

  f32x4 acc[4][4];
#pragma unroll
  for (int i = 0; i < 4; ++i)
#pragma unroll
    for (int j = 0; j < 4; ++j) acc[i][j] = (f32x4)0.0f;

  for (int k0 = 0; k0 < K; k0 += 64) {
    __syncthreads();
#pragma unroll
    for (int t = 0; t < 4; ++t) {
      int c = tid + 256 * t;
      int row = c >> 3, cc = c & 7;
      uint4 va = *(const uint4*)(A + (size_t)(m0 + row) * K + k0 + cc * 8);
      *(uint2*)&As[row][cc * 8]     = make_uint2(va.x, va.y);
      *(uint2*)&As[row][cc * 8 + 4] = make_uint2(va.z, va.w);
      uint4 vb = *(const uint4*)(Bw + (size_t)(n0 + row) * K + k0 + cc * 8);
      *(uint2*)&Bs[row][cc * 8]     = make_uint2(vb.x, vb.y);
      *(uint2*)&Bs[row][cc * 8 + 4] = make_uint2(vb.z, vb.w);
    }
    __syncthreads();
#pragma unroll
    for (int kk = 0; kk < 64; kk += 32) {
      bf16x8 af[4], bfr[4];
#pragma unroll
      for (int i = 0; i < 4; ++i) {
        int r = wr * 64 + i * 16 + lo;
        af[i] = mk8(*(const ushort4*)&As[r][kk + 4 * hi],
                    *(const ushort4*)&As[r][kk + 16 + 4 * hi]);
      }
#pragma unroll
      for (int j = 0; j < 4; ++j) {
        int r = wc * 64 + j * 16 + lo;
        bfr[j] = mk8(*(const ushort4*)&Bs[r][kk + 4 * hi],
                     *(const ushort4*)&Bs[r][kk + 16 + 4 * hi]);
      }
#pragma unroll
      for (int i = 0; i < 4; ++i)
#pragma unroll
        for (int j = 0; j < 4; ++j)
          acc[i][j] = __builtin_amdgcn_mfma_f32_16x16x32_bf16(af[i], bfr[j], acc[i][j], 0, 0, 0);
    }
  }
#pragma unroll
  for (int i = 0; i < 4; ++i) {
    int row = m0 + wr * 64 + i * 16 + 4 * hi;
#pragma unroll
    for (int j = 0; j < 4; ++j) {
      int col = n0 + wc * 64 + j * 16 + lo;
#pragma unroll
      for (int r = 0; r < 4; ++r) {
        float v = acc[i][j][r];
        if constexpr (OUT_BF16) {
          ((ushort*)Cout)[(size_t)(row + r) * N + col] = f2bf(v);
        } else {
          ((float*)Cout)[(size_t)(row + r) * N + col] = v;
        }
      }
    }
  }
}

// ---------------- fused RoPE + mean + causal attention per (b,h,g) — 8 waves ----------------
__global__ __launch_bounds__(512, 4) void attn1f(const ushort* __restrict__ qkv,
                                                 const float* __restrict__ fc,
                                                 const float* __restrict__ fs,
                                                 ushort* __restrict__ xo, float* __restrict__ attm,
                                                 float* __restrict__ yq, float* __restrict__ yk) {
  __shared__ ushort qs[144][68];
  __shared__ ushort ks[144][68];
  __shared__ ushort vt[64][148];     // V^T: vt[d][key]
  __shared__ ushort obuf[8][16][68]; // phase C; aliased as redL (6 KB) for the mean reduce
  float (*redL)[8][24] = reinterpret_cast<float(*)[8][24]>(&obuf[0][0][0]);
  const int blk = blockIdx.x;
  const int g = blk & 15, h = (blk >> 4) & 15, b = blk >> 8;
  const int tid = threadIdx.x;
  const int lane = tid & 63, wv = tid >> 6;
  const int lo = lane & 15, hi = lane >> 4;

  // zero V^T pad keys 128..147 (write-disjoint from staging) — no barrier needed
  if (tid < 320) {
    int d = tid / 5, ch = (tid % 5) * 4;
    *(ushort4*)&vt[d][128 + ch] = make_ushort4(0, 0, 0, 0);
  }

  // fused stage + rope + mean-partials (rows 0..127; thread owns cols c8..c8+7)
  const size_t rowbase = (size_t)(b * TT + g * TG) * (3 * CC) + h * HS;
  const int srow = tid >> 3;          // 0..63
  const int c8 = (tid & 7) * 8;
  float msq[8], msk[8], msv[8];
#pragma unroll
  for (int j = 0; j < 8; ++j) { msq[j] = 0.f; msk[j] = 0.f; msv[j] = 0.f; }
#pragma unroll
  for (int it = 0; it < 6; ++it) {
    const int part = it >> 1;          // 0:q 1:k 2:v (compile-time after unroll)
    const int s = srow + 64 * (it & 1);
    uint4 w = *(const uint4*)(qkv + rowbase + (size_t)s * (3 * CC) + part * CC + c8);
    ushort e[8];
    *(uint4*)e = w;
    if (part == 2) {
#pragma unroll
      for (int j = 0; j < 8; ++j) { msv[j] += bf2f(e[j]); vt[c8 + j][s] = e[j]; }
    } else {
      const int ts = g * TG + s;
      float4 cv = *(const float4*)&fc[ts * 32 + (c8 >> 1)];
      float4 sv = *(const float4*)&fs[ts * 32 + (c8 >> 1)];
      float a0 = bf2f(e[0]), a1 = bf2f(e[1]), a2 = bf2f(e[2]), a3 = bf2f(e[3]);
      float a4 = bf2f(e[4]), a5 = bf2f(e[5]), a6 = bf2f(e[6]), a7 = bf2f(e[7]);
      float r0 = a0 * cv.x - a1 * sv.x, r1 = a0 * sv.x + a1 * cv.x;
      float r2 = a2 * cv.y - a3 * sv.y, r3 = a2 * sv.y + a3 * cv.y;
      float r4 = a4 * cv.z - a5 * sv.z, r5 = a4 * sv.z + a5 * cv.z;
      float r6 = a6 * cv.w - a7 * sv.w, r7 = a6 * sv.w + a7 * cv.w;
      uint4 o;
      o.x = (unsigned)f2bf(r0) | ((unsigned)f2bf(r1) << 16);
      o.y = (unsigned)f2bf(r2) | ((unsigned)f2bf(r3) << 16);
      o.z = (unsigned)f2bf(r4) | ((unsigned)f2bf(r5) << 16);
      o.w = (unsigned)f2bf(r6) | ((unsigned)f2bf(r7) << 16);
      if (part == 0) {
        *(uint4*)&qs[s][c8] = o;
        msq[0] += r0; msq[1] += r1; msq[2] += r2; msq[3] += r3;
        msq[4] += r4; msq[5] += r5; msq[6] += r6; msq[7] += r7;
      } else {
        *(uint4*)&ks[s][c8] = o;
        msk[0] += r0; msk[1] += r1; msk[2] += r2; msk[3] += r3;
        msk[4] += r4; msk[5] += r5; msk[6] += r6; msk[7] += r7;
      }
    }
  }
  // reduce over s within wave (lanes ⊕8,16,32 share c8), then cross-wave via redL
#pragma unroll
  for (int j = 0; j < 8; ++j) {
    msq[j] += __shfl_xor(msq[j], 8); msq[j] += __shfl_xor(msq[j], 16); msq[j] += __shfl_xor(msq[j], 32);
    msk[j] += __shfl_xor(msk[j], 8); msk[j] += __shfl_xor(msk[j], 16); msk[j] += __shfl_xor(msk[j], 32);
    msv[j] += __shfl_xor(msv[j], 8); msv[j] += __shfl_xor(msv[j], 16); msv[j] += __shfl_xor(msv[j], 32);
  }
  if (lane < 8) {
#pragma unroll
    for (int j = 0; j < 8; ++j) {
      redL[wv][lane][j] = msq[j];
      redL[wv][lane][8 + j] = msk[j];
      redL[wv][lane][16 + j] = msv[j];
    }
  }
  __syncthreads();
  if (tid < 64) {
    const int cg = tid >> 3, j = tid & 7;
    float mq = 0.f, mk2 = 0.f, mv = 0.f;
#pragma unroll
    for (int w = 0; w < 8; ++w) {
      mq += redL[w][cg][j];
      mk2 += redL[w][cg][8 + j];
      mv += redL[w][cg][16 + j];
    }
    mq *= (1.0f / 128.0f); mk2 *= (1.0f / 128.0f); mv *= (1.0f / 128.0f);
    qs[128][tid] = f2bf(mq);
    ks[128][tid] = f2bf(mk2);
    vt[tid][128] = f2bf(mv);
    if (g < 15) {
      size_t yo = ((size_t)(b * 16 + h) * 15 + g) * 64 + tid;
      yq[yo] = mq; yk[yo] = mk2;
    }
  }
  __syncthreads();

  // attention: wave wv -> tile t=8-wv; wave 7 also t=0.
  // (stale qs/ks rows 129..143 contained by masking / discarded garbage-query cols)
#pragma unroll
  for (int ti = 0; ti < 2; ++ti) {
    const int t = (ti == 0) ? (8 - wv) : ((wv == 7) ? 0 : -1);
    if (t < 0) continue;
    const int q0 = t * 16;

    bf16x8 bq[2];
#pragma unroll
    for (int k2 = 0; k2 < 2; ++k2)
      bq[k2] = mk8(*(const ushort4*)&qs[q0 + lo][k2 * 32 + 4 * hi],
                   *(const ushort4*)&qs[q0 + lo][k2 * 32 + 16 + 4 * hi]);

    f32x4 sc[9];
#pragma unroll
    for (int n = 0; n < 9; ++n) sc[n] = (f32x4)0.0f;
#pragma unroll
    for (int n = 0; n < 9; ++n) {
      if (n > t) continue;
#pragma unroll
      for (int k2 = 0; k2 < 2; ++k2) {
        bf16x8 ak = mk8(*(const ushort4*)&ks[n * 16 + lo][k2 * 32 + 4 * hi],
                        *(const ushort4*)&ks[n * 16 + lo][k2 * 32 + 16 + 4 * hi]);
        sc[n] = __builtin_amdgcn_mfma_f32_16x16x32_bf16(ak, bq[k2], sc[n], 0, 0, 0);
      }
    }

    const int qi = q0 + lo;
    float mx = -INFINITY;
#pragma unroll
    for (int n = 0; n < 9; ++n) {
      if (n > t) continue;
#pragma unroll
      for (int r = 0; r < 4; ++r) {
        int kj = n * 16 + 4 * hi + r;
        float v = (kj <= qi) ? sc[n][r] * 0.125f : -INFINITY;
        sc[n][r] = v;
        mx = fmaxf(mx, v);
      }
    }
    mx = fmaxf(mx, __shfl_xor(mx, 16));
    mx = fmaxf(mx, __shfl_xor(mx, 32));
    float sum = 0.f;
#pragma unroll
    for (int n = 0; n < 9; ++n) {
      if (n > t) continue;
#pragma unroll
      for (int r = 0; r < 4; ++r) {
        float e = __expf(sc[n][r] - mx);
        sc[n][r] = e;
        sum += e;
      }
    }
    sum += __shfl_xor(sum, 16);
    sum += __shfl_xor(sum, 32);
    const float inv = 1.0f / sum;

    f32x4 oac[4];
#pragma unroll
    for (int m = 0; m < 4; ++m) oac[m] = (f32x4)0.0f;
#pragma unroll
    for (int s2 = 0; s2 < 5; ++s2) {
      if (s2 > (t >> 1)) continue;
      const int kt1ok = (2 * s2 + 1 <= t);
      bf16x8 pb;
#pragma unroll
      for (int e = 0; e < 4; ++e) pb[e] = (short)f2bf(sc[2 * s2][e] * inv);
      if (kt1ok) {
#pragma unroll
        for (int e = 0; e < 4; ++e) pb[e + 4] = (short)f2bf(sc[2 * s2 + 1][e] * inv);
      } else {
#pragma unroll
        for (int e = 0; e < 4; ++e) pb[e + 4] = 0;
      }
#pragma unroll
      for (int m = 0; m < 4; ++m) {
        ushort4 a0 = *(const ushort4*)&vt[m * 16 + lo][32 * s2 + 4 * hi];
        ushort4 a1 = kt1ok ? *(const ushort4*)&vt[m * 16 + lo][32 * s2 + 16 + 4 * hi]
                           : make_ushort4(0, 0, 0, 0);
        oac[m] = __builtin_amdgcn_mfma_f32_16x16x32_bf16(mk8(a0, a1), pb, oac[m], 0, 0, 0);
      }
    }

    if (t < 8) {
#pragma unroll
      for (int m = 0; m < 4; ++m)
#pragma unroll
        for (int r = 0; r < 4; ++r)
          obuf[wv][lo][m * 16 + 4 * hi + r] = f2bf(oac[m][r]);
#pragma unroll
      for (int it = 0; it < 4; ++it) {
        int idx = lane + 64 * it;
        int r = idx >> 4;
        int c4 = (idx & 15) * 4;
        uint2 val = *(const uint2*)&obuf[wv][r][c4];
        int tok = g * TG + t * 16 + r;
        *(uint2*)(xo + ((size_t)(b * TT + tok)) * CC + h * HS + c4) = val;
      }
    } else {
      if (lo == 0) {
#pragma unroll
        for (int m = 0; m < 4; ++m)
#pragma unroll
          for (int r = 0; r < 4; ++r)
            attm[(size_t)blk * 64 + m * 16 + 4 * hi + r] = oac[m][r];
      }
    }
  }
}

// ---------------- second (tiny) causal attention over 15 group-mean tokens ----------------
__global__ __launch_bounds__(64) void attn2(const float* __restrict__ yq,
                                            const float* __restrict__ yk,
                                            const float* __restrict__ attm,
                                            float* __restrict__ yv) {
  __shared__ float qs2[15][64], ks2[15][64], avs[15][64], srow[16];
  int bh = blockIdx.x, lane = threadIdx.x;
  for (int j = 0; j < 15; ++j) {
    qs2[j][lane] = yq[((size_t)bh * 15 + j) * 64 + lane];
    ks2[j][lane] = yk[((size_t)bh * 15 + j) * 64 + lane];
    avs[j][lane] = attm[((size_t)bh * 16 + j) * 64 + lane];
  }
  __syncthreads();
  for (int i = 0; i < 15; ++i) {
    float qv = qs2[i][lane];
    for (int j = 0; j <= i; ++j) {
      float t = qv * ks2[j][lane];
#pragma unroll
      for (int off = 32; off > 0; off >>= 1) t += __shfl_xor(t, off);
      if (lane == 0) srow[j] = t * 0.125f;
    }
    __syncthreads();
    float mx = -INFINITY;
    for (int j = 0; j <= i; ++j) mx = fmaxf(mx, srow[j]);
    float den = 0;
    for (int j = 0; j <= i; ++j) den += __expf(srow[j] - mx);
    float inv = 1.0f / den;
    float o = 0;
    for (int j = 0; j <= i; ++j) o += __expf(srow[j] - mx) * inv * avs[j][lane];
    yv[((size_t)bh * 15 + i) * 64 + lane] = o;
    __syncthreads();
  }
}

extern "C" void kernel_launch(void* const* d_in, const int* in_sizes, int n_in,
                              void* d_out, int out_size, void* d_ws, size_t ws_size,
                              hipStream_t stream) {
  const float* x      = (const float*)d_in[0];
  const float* w_attn = (const float*)d_in[1];
  const float* w_proj = (const float*)d_in[2];
  const float* fc     = (const float*)d_in[3];
  const float* fs     = (const float*)d_in[4];
  float* out = (float*)d_out;

  char* ws = (char*)d_ws;
  ushort* xb   = (ushort*)(ws);               // x bf16; dead after qkv gemm
  ushort* xo   = (ushort*)(ws);               // reuse xb region (attn1f output)
  ushort* wab  = (ushort*)(ws + 16777216);    // dead after qkv gemm
  float*  attm = (float*) (ws + 16777216);    // reuse wab region
  ushort* wpb  = (ushort*)(ws + 23068672);
  ushort* qkv  = (ushort*)(ws + 25165824);    // (B*T) x 3C bf16 -> end 75,497,472

  float* yq = out + 8388608;
  float* yk = out + 8450048;
  float* yv = out + 8511488;

  cvt3<<<2048, 256, 0, stream>>>(x, w_attn, w_proj, xb, wab, wpb);
  gemm_bt<true><<<dim3(24, 64), 256, 0, stream>>>(xb, wab, qkv, 8192, 3072, 1024);
  attn1f<<<1024, 512, 0, stream>>>(qkv, fc, fs, xo, attm, yq, yk);
  attn2<<<64, 64, 0, stream>>>(yq, yk, attm, yv);
  gemm_bt<false><<<dim3(8, 64), 256, 0, stream>>>(xo, wpb, out, 8192, 1024, 1024);
}